// Round 5
// baseline (150.670 us; speedup 1.0000x reference)
//
#include <hip/hip_runtime.h>
#include <math.h>

#define NB 8
#define NF 16384
#define NH 256
#define CL 4                   // steps per chunk
#define CPB (NF / CL)          // 4096 chunks per batch
#define NCHUNK (NB * CPB)      // 32768 chunks
#define NROW (NB * NF)         // 131072 rows
#define SPT (CPB / 256)        // 16 summaries per phaseB thread
#define RPL 4                  // rows per lane in the MLP j-loop

#define GZ -9.81007f

// ws layout (floats):
//  rec:   NROW*8     transposed records [i*NCHUNK+c]*8 = ca3, cg3, dt, pad
//  summ:  NCHUNK*12  (P4, T,S,Ux,Uy, Uz,Wx,Wy,Wz)
//  state: NCHUNK*12  (px,py,pz,vx, vy,vz,qw,qx, qy,qz,pad,pad)
#define REC_OFF    0
#define SUMM_OFF   ((size_t)NROW * 8)
#define STATE_OFF  (SUMM_OFF + (size_t)NCHUNK * 12)

__device__ __forceinline__ void qrotate(float qw, float qx, float qy, float qz,
                                        float vx, float vy, float vz,
                                        float& ox, float& oy, float& oz) {
    float tx = qy*vz - qz*vy + qw*vx;
    float ty = qz*vx - qx*vz + qw*vy;
    float tz = qx*vy - qy*vx + qw*vz;
    ox = vx + 2.0f*(qy*tz - qz*ty);
    oy = vy + 2.0f*(qz*tx - qx*tz);
    oz = vz + 2.0f*(qx*ty - qy*tx);
}

__device__ __forceinline__ void qmulf(float aw, float ax, float ay, float az,
                                      float bw, float bx, float by, float bz,
                                      float& ow, float& ox, float& oy, float& oz) {
    ow = aw*bw - ax*bx - ay*by - az*bz;
    ox = aw*bx + bw*ax + (ay*bz - az*by);
    oy = aw*by + bw*ay + (az*bx - ax*bz);
    oz = aw*bz + bw*az + (ax*by - ay*bx);
}

// quat_exp(w), |w| <= ~0.03: fp32-exact Taylor of cos(|w|/2), sin(|w|/2)/|w|.
__device__ __forceinline__ void qexpw(float wx, float wy, float wz,
                                      float& ew, float& ex, float& ey, float& ez) {
    float th2 = wx*wx + wy*wy + wz*wz + 1e-16f;
    float h2  = 0.25f * th2;
    ew = 1.0f + h2*(-0.5f + h2*((1.0f/24.0f) - h2*(1.0f/720.0f)));
    float sh = 0.5f + h2*(-(1.0f/12.0f) + h2*(1.0f/240.0f));
    ex = wx*sh; ey = wy*sh; ez = wz*sh;
}

__device__ __forceinline__ float gelu_tanh(float h) {
    float h2 = h*h;
    float u2 = h*(1.5957691216057308f + 0.0713548162726009f*h2);
    float t  = 1.0f - __fdividef(2.0f, 1.0f + __expf(u2));
    float a  = 0.5f*h;
    return a + a*t;
}

struct Sum { float Pw, Px, Py, Pz, T, S, Ux, Uy, Uz, Wx, Wy, Wz; };

__device__ __forceinline__ Sum compose(const Sum& a, const Sum& b) {
    Sum r;
    float RUx, RUy, RUz, RWx, RWy, RWz;
    qrotate(a.Pw, a.Px, a.Py, a.Pz, b.Ux, b.Uy, b.Uz, RUx, RUy, RUz);
    qrotate(a.Pw, a.Px, a.Py, a.Pz, b.Wx, b.Wy, b.Wz, RWx, RWy, RWz);
    r.Ux = a.Ux + RUx;  r.Uy = a.Uy + RUy;  r.Uz = a.Uz + RUz;
    r.Wx = a.Wx + a.Ux*b.T + RWx;
    r.Wy = a.Wy + a.Uy*b.T + RWy;
    r.Wz = a.Wz + a.Uz*b.T + RWz;
    r.S  = a.S + a.T*b.T + b.S;
    r.T  = a.T + b.T;
    float nw, nx, ny, nz;
    qmulf(a.Pw, a.Px, a.Py, a.Pz, b.Pw, b.Px, b.Py, b.Pz, nw, nx, ny, nz);
    float inv = 1.0f / sqrtf(nw*nw + nx*nx + ny*ny + nz*nz);
    r.Pw = nw*inv; r.Px = nx*inv; r.Py = ny*inv; r.Pz = nz*inv;
    return r;
}

__device__ __forceinline__ Sum shflDownSum(const Sum& s, int d) {
    Sum r;
    r.Pw = __shfl_down(s.Pw, d, 64); r.Px = __shfl_down(s.Px, d, 64);
    r.Py = __shfl_down(s.Py, d, 64); r.Pz = __shfl_down(s.Pz, d, 64);
    r.T  = __shfl_down(s.T,  d, 64); r.S  = __shfl_down(s.S,  d, 64);
    r.Ux = __shfl_down(s.Ux, d, 64); r.Uy = __shfl_down(s.Uy, d, 64);
    r.Uz = __shfl_down(s.Uz, d, 64); r.Wx = __shfl_down(s.Wx, d, 64);
    r.Wy = __shfl_down(s.Wy, d, 64); r.Wz = __shfl_down(s.Wz, d, 64);
    return r;
}

struct State { float px, py, pz, vx, vy, vz, qw, qx, qy, qz; };

__device__ __forceinline__ State applySum(const State& st, const Sum& s) {
    State r;
    float RUx, RUy, RUz, RWx, RWy, RWz;
    qrotate(st.qw, st.qx, st.qy, st.qz, s.Ux, s.Uy, s.Uz, RUx, RUy, RUz);
    qrotate(st.qw, st.qx, st.qy, st.qz, s.Wx, s.Wy, s.Wz, RWx, RWy, RWz);
    r.px = st.px + st.vx*s.T + RWx;
    r.py = st.py + st.vy*s.T + RWy;
    r.pz = st.pz + st.vz*s.T + RWz + GZ*s.S;
    r.vx = st.vx + RUx;
    r.vy = st.vy + RUy;
    r.vz = st.vz + RUz + GZ*s.T;
    float nw, nx, ny, nz;
    qmulf(st.qw, st.qx, st.qy, st.qz, s.Pw, s.Px, s.Py, s.Pz, nw, nx, ny, nz);
    float inv = 1.0f / sqrtf(nw*nw + nx*nx + ny*ny + nz*nz);
    r.qw = nw*inv; r.qx = nx*inv; r.qy = ny*inv; r.qz = nz*inv;
    return r;
}

__device__ __forceinline__ Sum loadSum(const float* __restrict__ p, int c) {
    const float* sp = p + (size_t)c*12;
    float4 a0 = ((const float4*)sp)[0];
    float4 a1 = ((const float4*)sp)[1];
    float4 a2 = ((const float4*)sp)[2];
    Sum s;
    s.Pw = a0.x; s.Px = a0.y; s.Py = a0.z; s.Pz = a0.w;
    s.T = a1.x; s.S = a1.y; s.Ux = a1.z; s.Uy = a1.w;
    s.Uz = a2.x; s.Wx = a2.y; s.Wy = a2.z; s.Wz = a2.w;
    return s;
}

// ---- Kernel 1: MLP + record pack + per-chunk summaries (fused phaseA).
// 4 waves split 256 hidden units; each lane handles RPL=4 rows -> 256 rows/block.
// Scalar weight loads amortized 4x (the R4 profile showed s_load-latency stalls).
__global__ __launch_bounds__(256)
void mlp_summ_kernel(const float* __restrict__ acc, const float* __restrict__ gyro,
                     const float* __restrict__ dtp,
                     const float* __restrict__ Wenc, const float* __restrict__ benc,
                     const float* __restrict__ Wdec, const float* __restrict__ bdec,
                     float* __restrict__ out, float* __restrict__ rec,
                     float* __restrict__ summ) {
    __shared__ float part[4][256][8];           // [wave][row_local][6 acc]
    int t = threadIdx.x;
    int lane = t & 63;
    int wv = __builtin_amdgcn_readfirstlane(t >> 6);
    int base = blockIdx.x * 256;

    float ax[RPL], ay[RPL], az[RPL], gx[RPL], gy[RPL], gz[RPL];
    float c0[RPL], c1[RPL], c2[RPL], c3[RPL], c4[RPL], c5[RPL];
    #pragma unroll
    for (int r = 0; r < RPL; r++) {
        int n = base + r*64 + lane;
        ax[r] = acc[n*3+0]; ay[r] = acc[n*3+1]; az[r] = acc[n*3+2];
        gx[r] = gyro[n*3+0]; gy[r] = gyro[n*3+1]; gz[r] = gyro[n*3+2];
        c0[r]=0; c1[r]=0; c2[r]=0; c3[r]=0; c4[r]=0; c5[r]=0;
    }
    int j0 = wv * 64;
    #pragma unroll 4
    for (int jj = 0; jj < 64; jj++) {
        int j = j0 + jj;                        // wave-uniform -> s_load
        float w0 = Wenc[0*NH+j], w1 = Wenc[1*NH+j], w2 = Wenc[2*NH+j];
        float w3 = Wenc[3*NH+j], w4 = Wenc[4*NH+j], w5 = Wenc[5*NH+j];
        float bb = benc[j];
        const float* dw = Wdec + j*6;
        float d0 = dw[0], d1 = dw[1], d2 = dw[2], d3 = dw[3], d4 = dw[4], d5 = dw[5];
        #pragma unroll
        for (int r = 0; r < RPL; r++) {
            float h = bb + w0*ax[r] + w1*ay[r] + w2*az[r] + w3*gx[r] + w4*gy[r] + w5*gz[r];
            float g = gelu_tanh(h);
            c0[r] += g*d0; c1[r] += g*d1; c2[r] += g*d2;
            c3[r] += g*d3; c4[r] += g*d4; c5[r] += g*d5;
        }
    }
    #pragma unroll
    for (int r = 0; r < RPL; r++) {
        float* pp = part[wv][r*64 + lane];
        *(float4*)pp     = make_float4(c0[r], c1[r], c2[r], c3[r]);
        *(float2*)(pp+4) = make_float2(c4[r], c5[r]);
    }
    __syncthreads();

    // epilogue: thread t owns row n = base + t
    int n = base + t;
    float4 A = *(const float4*)part[0][t];
    float2 B = *(const float2*)(part[0][t]+4);
    #pragma unroll
    for (int w = 1; w < 4; w++) {
        float4 A2 = *(const float4*)part[w][t];
        float2 B2 = *(const float2*)(part[w][t]+4);
        A.x += A2.x; A.y += A2.y; A.z += A2.z; A.w += A2.w;
        B.x += B2.x; B.y += B2.y;
    }
    float e0 = A.x + bdec[0], e1 = A.y + bdec[1], e2 = A.z + bdec[2];
    float e3 = A.w + bdec[3], e4 = B.x + bdec[4], e5 = B.y + bdec[5];
    float* ob = out + (size_t)n*16;
    *(float2*)(ob+10) = make_float2(e0, e1);
    *(float4*)(ob+12) = make_float4(e2, e3, e4, e5);

    float dtv = dtp[n];
    float rax = acc[n*3+0], ray = acc[n*3+1], raz = acc[n*3+2];
    float rgx = gyro[n*3+0], rgy = gyro[n*3+1], rgz = gyro[n*3+2];
    float cax = e0+rax, cay = e1+ray, caz = e2+raz;
    float cgx = e3+rgx, cgy = e4+rgy, cgz = e5+rgz;
    int ci = n >> 2, ii = n & 3;                // CL = 4
    float* rp = rec + (size_t)(ii*NCHUNK + ci)*8;
    *(float4*)rp     = make_float4(cax, cay, caz, cgx);
    *(float4*)(rp+4) = make_float4(cgy, cgz, dtv, 0.0f);

    // per-step summary, tree-composed over 4 consecutive lanes (rows 4-aligned in wave)
    Sum s;
    float hdt2 = 0.5f*dtv*dtv;
    qexpw(cgx*dtv, cgy*dtv, cgz*dtv, s.Pw, s.Px, s.Py, s.Pz);
    s.T = dtv; s.S = hdt2;
    s.Ux = cax*dtv;  s.Uy = cay*dtv;  s.Uz = caz*dtv;
    s.Wx = cax*hdt2; s.Wy = cay*hdt2; s.Wz = caz*hdt2;
    Sum nb = shflDownSum(s, 1);
    s = compose(s, nb);          // valid at even lanes
    nb = shflDownSum(s, 2);
    s = compose(s, nb);          // valid at lane%4==0
    if ((t & 3) == 0) {
        float* sp = summ + (size_t)(n >> 2)*12;
        ((float4*)sp)[0] = make_float4(s.Pw, s.Px, s.Py, s.Pz);
        ((float4*)sp)[1] = make_float4(s.T, s.S, s.Ux, s.Uy);
        ((float4*)sp)[2] = make_float4(s.Uz, s.Wx, s.Wy, s.Wz);
    }
}

// ---- Kernel 2: per-batch parallel scan of 4096 summaries ----
__global__ __launch_bounds__(256)
void phaseB(const float* __restrict__ summ, float* __restrict__ state,
            const float* __restrict__ init_pos, const float* __restrict__ init_vel,
            const float* __restrict__ init_rot) {
    __shared__ float lds[256*12];
    int b = blockIdx.x, t = threadIdx.x;
    int c0 = b*CPB + t*SPT;
    Sum agg = loadSum(summ, c0);
    for (int k = 1; k < SPT; k++) agg = compose(agg, loadSum(summ, c0+k));

    float* mine = lds + t*12;
    mine[0]=agg.Pw; mine[1]=agg.Px; mine[2]=agg.Py; mine[3]=agg.Pz;
    mine[4]=agg.T;  mine[5]=agg.S;  mine[6]=agg.Ux; mine[7]=agg.Uy;
    mine[8]=agg.Uz; mine[9]=agg.Wx; mine[10]=agg.Wy; mine[11]=agg.Wz;
    __syncthreads();
    for (int d = 1; d < 256; d <<= 1) {
        Sum left;
        bool have = (t >= d);
        if (have) {
            const float* lp = lds + (t-d)*12;
            left.Pw=lp[0]; left.Px=lp[1]; left.Py=lp[2]; left.Pz=lp[3];
            left.T=lp[4];  left.S=lp[5];  left.Ux=lp[6]; left.Uy=lp[7];
            left.Uz=lp[8]; left.Wx=lp[9]; left.Wy=lp[10]; left.Wz=lp[11];
        }
        __syncthreads();
        if (have) {
            agg = compose(left, agg);
            mine[0]=agg.Pw; mine[1]=agg.Px; mine[2]=agg.Py; mine[3]=agg.Pz;
            mine[4]=agg.T;  mine[5]=agg.S;  mine[6]=agg.Ux; mine[7]=agg.Uy;
            mine[8]=agg.Uz; mine[9]=agg.Wx; mine[10]=agg.Wy; mine[11]=agg.Wz;
        }
        __syncthreads();
    }
    State st;
    st.px = init_pos[b*3+0]; st.py = init_pos[b*3+1]; st.pz = init_pos[b*3+2];
    st.vx = init_vel[b*3+0]; st.vy = init_vel[b*3+1]; st.vz = init_vel[b*3+2];
    st.qw = init_rot[b*4+0]; st.qx = init_rot[b*4+1]; st.qy = init_rot[b*4+2]; st.qz = init_rot[b*4+3];
    if (t > 0) {
        const float* lp = lds + (t-1)*12;
        Sum pre;
        pre.Pw=lp[0]; pre.Px=lp[1]; pre.Py=lp[2]; pre.Pz=lp[3];
        pre.T=lp[4];  pre.S=lp[5];  pre.Ux=lp[6]; pre.Uy=lp[7];
        pre.Uz=lp[8]; pre.Wx=lp[9]; pre.Wy=lp[10]; pre.Wz=lp[11];
        st = applySum(st, pre);
    }
    for (int k = 0; k < SPT; k++) {
        float* sp = state + (size_t)(c0+k)*12;
        ((float4*)sp)[0] = make_float4(st.px, st.py, st.pz, st.vx);
        ((float4*)sp)[1] = make_float4(st.vy, st.vz, st.qw, st.qx);
        ((float4*)sp)[2] = make_float4(st.qy, st.qz, 0.0f, 0.0f);
        st = applySum(st, loadSum(summ, c0+k));
    }
}

// ---- Kernel 3: replay chunks, direct row writes (L2 merges the 64B rows) ----
__global__ __launch_bounds__(256)
void phaseC(const float* __restrict__ rec, const float* __restrict__ state,
            float* __restrict__ out) {
    int c = blockIdx.x * 256 + threadIdx.x;
    const float* sp = state + (size_t)c*12;
    float4 a0 = ((const float4*)sp)[0];
    float4 a1 = ((const float4*)sp)[1];
    float4 a2 = ((const float4*)sp)[2];
    float px = a0.x, py = a0.y, pz = a0.z;
    float vx = a0.w, vy = a1.x, vz = a1.y;
    float qw = a1.z, qx = a1.w, qy = a2.x, qz = a2.y;
    const float4* r = (const float4*)rec;
    float* obase = out + (size_t)c*CL*16;
    #pragma unroll
    for (int i = 0; i < CL; i++) {
        float4 r0 = r[(size_t)(i*NCHUNK + c)*2];
        float4 r1 = r[(size_t)(i*NCHUNK + c)*2 + 1];
        float dtv = r1.z;
        float awx, awy, awz;
        qrotate(qw, qx, qy, qz, r0.x, r0.y, r0.z, awx, awy, awz);
        awz += GZ;
        float hdt2 = 0.5f*dtv*dtv;
        px += vx*dtv + awx*hdt2;
        py += vy*dtv + awy*hdt2;
        pz += vz*dtv + awz*hdt2;
        vx += awx*dtv; vy += awy*dtv; vz += awz*dtv;
        float ew, ex, ey, ez, nw, nx, ny, nz;
        qexpw(r0.w*dtv, r1.x*dtv, r1.y*dtv, ew, ex, ey, ez);
        qmulf(qw, qx, qy, qz, ew, ex, ey, ez, nw, nx, ny, nz);
        float inv = 1.0f / sqrtf(nw*nw + nx*nx + ny*ny + nz*nz);
        qw = nw*inv; qx = nx*inv; qy = ny*inv; qz = nz*inv;
        float* ob = obase + (size_t)i*16;
        *(float4*)(ob+0) = make_float4(px, py, pz, vx);
        *(float4*)(ob+4) = make_float4(vy, vz, qw, qx);
        *(float2*)(ob+8) = make_float2(qy, qz);
    }
}

extern "C" void kernel_launch(void* const* d_in, const int* in_sizes, int n_in,
                              void* d_out, int out_size, void* d_ws, size_t ws_size,
                              hipStream_t stream) {
    const float* acc      = (const float*)d_in[0];
    const float* gyro     = (const float*)d_in[1];
    const float* dt       = (const float*)d_in[2];
    const float* init_pos = (const float*)d_in[3];
    const float* init_vel = (const float*)d_in[4];
    const float* init_rot = (const float*)d_in[5];
    const float* Wenc     = (const float*)d_in[6];
    const float* benc     = (const float*)d_in[7];
    const float* Wdec     = (const float*)d_in[8];
    const float* bdec     = (const float*)d_in[9];
    float* out = (float*)d_out;
    float* ws  = (float*)d_ws;
    float* rec   = ws + REC_OFF;
    float* summ  = ws + SUMM_OFF;
    float* state = ws + STATE_OFF;

    mlp_summ_kernel<<<NROW/256, 256, 0, stream>>>(acc, gyro, dt, Wenc, benc, Wdec, bdec,
                                                  out, rec, summ);
    phaseB<<<NB, 256, 0, stream>>>(summ, state, init_pos, init_vel, init_rot);
    phaseC<<<NCHUNK/256, 256, 0, stream>>>(rec, state, out);
}